// Round 2
// baseline (88264.203 us; speedup 1.0000x reference)
//
#include <hip/hip_runtime.h>
#include <cstddef>
#include <cstdint>

// Problem constants
#define TSTEPS 256
#define HDIM 50
#define BTOT 4096
#define MBL 8        // batch elements per block
#define NTHR 256     // threads per block (4 waves)
#define NGR 200      // 4*HDIM gate rows

// Inter-layer h timeseries buffer: (B, T, H) f32 = 209.7 MB.
// Fully rewritten by layer 0 each call before any read -> deterministic.
__device__ float g_hbuf[(size_t)BTOT * TSTEPS * HDIM];

__device__ __forceinline__ float fast_sigmoid(float x) {
    float e = __builtin_amdgcn_exp2f(-1.4426950408889634f * x);
    return __builtin_amdgcn_rcpf(1.0f + e);
}
__device__ __forceinline__ float fast_tanh(float x) {
    float e = __builtin_amdgcn_exp2f(2.8853900817779268f * x);
    return 1.0f - 2.0f * __builtin_amdgcn_rcpf(1.0f + e);
}

// Weights-in-registers LSTM layer.
// Thread tid = gate-row gr (active gr<200), holds W[gr][0..JP) in VGPRs.
// Activations [x_t | h_t] in LDS; gate-FMA reads are wave-uniform broadcasts.
// Gate values exchanged via stride-9 LDS buffer; cell update by (n,b) items.
template<int D, int JP, bool XIN_HBUF, bool WRITE_H, bool LAST>
__global__ __launch_bounds__(NTHR, 2) void lstm_layer(
    const float* xin_p,
    const float* __restrict__ w_ih, const float* __restrict__ w_hh,
    const float* __restrict__ b_ih, const float* __restrict__ b_hh,
    const float* __restrict__ w_fc, const float* __restrict__ b_fc,
    float* __restrict__ out)
{
    constexpr int JTOT = D + HDIM;
    constexpr int XR = (MBL * D + NTHR - 1) / NTHR;

    __shared__ float Ab[2][MBL][JP];          // activation double buffer
    __shared__ float Gl[NGR * (MBL + 1)];     // gate exchange, stride 9 (odd -> conflict-free)

    const int tid = threadIdx.x;
    const int gr  = tid;                      // gate row
    const bool act = gr < NGR;
    const bool istanh = (gr >= 2 * HDIM) && (gr < 3 * HDIM);  // gate type g (split order i,f,g,o)
    const int b0  = blockIdx.x * MBL;

    const float* xin = XIN_HBUF ? (const float*)g_hbuf : xin_p;

    // ---- prologue ----
    for (int i = tid; i < 2 * MBL * JP; i += NTHR) ((float*)Ab)[i] = 0.0f;

    // weights -> registers (fully unrolled, static indices only)
    float w[JP];
    #pragma unroll
    for (int j = 0; j < JP; ++j) {
        float v = 0.0f;
        if (j < JTOT && act)
            v = (j < D) ? w_ih[gr * D + j] : w_hh[gr * HDIM + (j - D)];
        w[j] = v;
    }
    const float bias = act ? (b_ih[gr] + b_hh[gr]) : 0.0f;

    // x_0
    for (int i = tid; i < MBL * D; i += NTHR) {
        int b = i / D, j = i % D;
        Ab[0][b][j] = xin[((size_t)(b0 + b) * TSTEPS + 0) * D + j];
    }

    float cst[2] = {0.0f, 0.0f};   // cell state for items tid, tid+NTHR
    __syncthreads();

    // ---- main scan ----
    for (int t = 0; t < TSTEPS; ++t) {
        const int cur = t & 1, nxt = cur ^ 1;

        // prefetch x_{t+1} (global -> regs, overlaps gate compute)
        float xr[XR];
        if (t + 1 < TSTEPS) {
            #pragma unroll
            for (int k = 0; k < XR; ++k) {
                int idx = tid + k * NTHR;
                if (idx < MBL * D) {
                    int b = idx / D, j = idx % D;
                    xr[k] = xin[((size_t)(b0 + b) * TSTEPS + (t + 1)) * D + j];
                }
            }
        }

        // gates: acc[b] = bias + sum_j w[j] * a[b][j]  (activation reads = broadcast)
        float acc[MBL];
        #pragma unroll
        for (int b = 0; b < MBL; ++b) acc[b] = bias;

        #pragma unroll
        for (int jb = 0; jb < JP / 4; ++jb) {
            float4 av[MBL];
            #pragma unroll
            for (int b = 0; b < MBL; ++b)
                av[b] = *(const float4*)&Ab[cur][b][jb * 4];
            #pragma unroll
            for (int b = 0; b < MBL; ++b) {
                acc[b] = fmaf(w[jb * 4 + 0], av[b].x, acc[b]);
                acc[b] = fmaf(w[jb * 4 + 1], av[b].y, acc[b]);
                acc[b] = fmaf(w[jb * 4 + 2], av[b].z, acc[b]);
                acc[b] = fmaf(w[jb * 4 + 3], av[b].w, acc[b]);
            }
        }

        // nonlinearity in gate-row thread, exchange via LDS
        if (act) {
            #pragma unroll
            for (int b = 0; b < MBL; ++b) {
                float v = istanh ? fast_tanh(acc[b]) : fast_sigmoid(acc[b]);
                Gl[gr * (MBL + 1) + b] = v;
            }
        }
        __syncthreads();

        // cell update: items (n,b), 400 items over 256 threads
        #pragma unroll
        for (int it = 0; it < 2; ++it) {
            int i = tid + it * NTHR;
            if (i < HDIM * MBL) {
                int n = i >> 3, b = i & 7;
                float ig = Gl[(0 * HDIM + n) * (MBL + 1) + b];
                float fg = Gl[(1 * HDIM + n) * (MBL + 1) + b];
                float gg = Gl[(2 * HDIM + n) * (MBL + 1) + b];
                float og = Gl[(3 * HDIM + n) * (MBL + 1) + b];
                float c  = fmaf(fg, cst[it], ig * gg);
                cst[it] = c;
                float h = og * fast_tanh(c);
                Ab[nxt][b][D + n] = h;
                if (WRITE_H)
                    g_hbuf[((size_t)(b0 + b) * TSTEPS + t) * HDIM + n] = h;
            }
        }

        // commit prefetched x_{t+1}
        if (t + 1 < TSTEPS) {
            #pragma unroll
            for (int k = 0; k < XR; ++k) {
                int idx = tid + k * NTHR;
                if (idx < MBL * D) {
                    int b = idx / D, j = idx % D;
                    Ab[nxt][b][j] = xr[k];
                }
            }
        }
        __syncthreads();
    }

    if (LAST) {
        // h_255 is in Ab[0][b][D..D+50)
        if (tid < MBL * 6) {
            int b = tid / 6, o = tid % 6;
            float a = b_fc[o];
            #pragma unroll
            for (int n = 0; n < HDIM; ++n)
                a = fmaf(w_fc[o * HDIM + n], Ab[0][b][D + n], a);
            out[(size_t)(b0 + b) * 6 + o] = a;
        }
    }
}

extern "C" void kernel_launch(void* const* d_in, const int* in_sizes, int n_in,
                              void* d_out, int out_size, void* d_ws, size_t ws_size,
                              hipStream_t stream) {
    (void)in_sizes; (void)n_in; (void)d_ws; (void)ws_size; (void)out_size;

    const float* x     = (const float*)d_in[0];
    const float* w_ih0 = (const float*)d_in[1];
    const float* w_hh0 = (const float*)d_in[2];
    const float* b_ih0 = (const float*)d_in[3];
    const float* b_hh0 = (const float*)d_in[4];
    const float* w_ih1 = (const float*)d_in[5];
    const float* w_hh1 = (const float*)d_in[6];
    const float* b_ih1 = (const float*)d_in[7];
    const float* b_hh1 = (const float*)d_in[8];
    const float* w_ih2 = (const float*)d_in[9];
    const float* w_hh2 = (const float*)d_in[10];
    const float* b_ih2 = (const float*)d_in[11];
    const float* b_hh2 = (const float*)d_in[12];
    const float* w_fc  = (const float*)d_in[13];
    const float* b_fc  = (const float*)d_in[14];
    float* out = (float*)d_out;

    dim3 grid(BTOT / MBL), block(NTHR);
    lstm_layer<8,  60,  false, true,  false><<<grid, block, 0, stream>>>(
        x,       w_ih0, w_hh0, b_ih0, b_hh0, nullptr, nullptr, out);
    lstm_layer<50, 100, true,  true,  false><<<grid, block, 0, stream>>>(
        nullptr, w_ih1, w_hh1, b_ih1, b_hh1, nullptr, nullptr, out);
    lstm_layer<50, 100, true,  false, true ><<<grid, block, 0, stream>>>(
        nullptr, w_ih2, w_hh2, b_ih2, b_hh2, w_fc,    b_fc,    out);
}

// Round 3
// 1030.408 us; speedup vs baseline: 85.6595x; 85.6595x over previous
//
#include <hip/hip_runtime.h>
#include <hip/hip_bf16.h>
#include <cstddef>

#define T_STEPS 256
#define BTOT 4096
#define MBK 16       // batches per block
#define NTHR 256     // 4 waves
#define KP 72        // padded K stride (bf16 elems) for LDS activation tiles
#define SP 212       // C exchange LDS row stride (floats)
#define XCOLS 52     // packed inter-layer timeseries cols (50 + pad to /4)

typedef __attribute__((ext_vector_type(8))) short  short8;   // bf16 MFMA frag (4 VGPR)
typedef __attribute__((ext_vector_type(4))) short  short4v;
typedef __attribute__((ext_vector_type(4))) float  f32x4;
typedef __attribute__((ext_vector_type(4))) unsigned uint4v;

// Inter-layer timeseries, (hi<<16)|lo packed bf16 pair per value ~= fp32.
// .bss zero-init at load; cols 50..51 additionally force-zeroed at stage time.
__device__ unsigned g_x01[(size_t)BTOT * T_STEPS * XCOLS];
__device__ unsigned g_x12[(size_t)BTOT * T_STEPS * XCOLS];

__device__ __forceinline__ float fast_sigmoid(float x) {
    float e = __builtin_amdgcn_exp2f(-1.4426950408889634f * x);
    return __builtin_amdgcn_rcpf(1.0f + e);
}
__device__ __forceinline__ float fast_tanh(float x) {
    float e = __builtin_amdgcn_exp2f(2.8853900817779268f * x);
    return 1.0f - 2.0f * __builtin_amdgcn_rcpf(1.0f + e);
}
__device__ __forceinline__ unsigned short f2bf(float x) {
    union { __hip_bfloat16 b; unsigned short s; } u;
    u.b = __float2bfloat16(x);
    return u.s;
}
__device__ __forceinline__ float bf2f(unsigned short s) {
    union { unsigned u; float f; } v; v.u = (unsigned)s << 16; return v.f;
}

// One LSTM layer, bf16-split MFMA recurrence, input-GEMM fused.
// Gate order reindexed N' = 4*n + g (g: 0=i,1=f,2=g,3=o), N'=0..199, 13 n-tiles of 16.
// Wave w owns n-tiles [base_w, base_w+ntw): {0..3},{4..6},{7..9},{10..12}.
// B-frags (weights, hi/lo) in VGPRs; A-frags built per step from LDS h/x tiles.
template<int D, int INSEL, int OUTSEL>
__global__ __launch_bounds__(NTHR, 1) void lstm_mfma(
    const float* __restrict__ xf,           // INSEL==0 input (B,T,8) f32
    const float* __restrict__ w_ih, const float* __restrict__ w_hh,
    const float* __restrict__ b_ih, const float* __restrict__ b_hh,
    const float* __restrict__ w_fc, const float* __restrict__ b_fc,
    float* __restrict__ out)
{
    constexpr int  KX   = (D + 31) / 32;     // k-steps for x part (1 or 2)
    constexpr bool LAST = (OUTSEL == 0);

    const unsigned* xp  = (INSEL == 1) ? g_x01 : g_x12;     // INSEL 0 unused
    unsigned*      xout = (OUTSEL == 1) ? g_x01 : g_x12;    // OUTSEL 0 unused

    __shared__ __align__(16) short h_hi[MBK * KP], h_lo[MBK * KP];
    __shared__ __align__(16) short x_hi[2][MBK * KP], x_lo[2][MBK * KP];
    __shared__ __align__(16) float Cl[MBK * SP];
    __shared__ __align__(16) float hf[MBK * 56];

    const int tid  = threadIdx.x;
    const int w    = tid >> 6;
    const int lane = tid & 63;
    const int col  = lane & 15;      // = N' col within tile = A-row (batch)
    const int kg   = lane >> 4;      // k-group 0..3
    const int b0   = blockIdx.x * MBK;
    const int base = w ? 3 * w + 1 : 0;
    const int ntw  = w ? 3 : 4;

    // ---- prologue: zero LDS act tiles ----
    for (int i = tid; i < MBK * KP; i += NTHR) {
        h_hi[i] = 0; h_lo[i] = 0;
        x_hi[0][i] = 0; x_hi[1][i] = 0; x_lo[0][i] = 0; x_lo[1][i] = 0;
    }

    // ---- weights -> B-frags (hi/lo), bias per (q,col) ----
    short8 Bxh[4][KX], Bxl[4][KX], Bhh[4][2], Bhl[4][2];
    float  bv[4];
    #pragma unroll
    for (int q = 0; q < 4; ++q) {
        int tile = base + q;
        int gp = tile * 16 + col;                        // N'
        int gr = (gp < 200) ? ((gp & 3) * 50 + (gp >> 2)) : -1;
        bv[q] = (gr >= 0) ? (b_ih[gr] + b_hh[gr]) : 0.0f;
        #pragma unroll
        for (int ks = 0; ks < KX; ++ks)
            #pragma unroll
            for (int e = 0; e < 8; ++e) {
                int k = ks * 32 + kg * 8 + e;
                float v = (gr >= 0 && k < D) ? w_ih[gr * D + k] : 0.0f;
                unsigned short hb = f2bf(v);
                Bxh[q][ks][e] = (short)hb;
                Bxl[q][ks][e] = (short)f2bf(v - bf2f(hb));
            }
        #pragma unroll
        for (int ks = 0; ks < 2; ++ks)
            #pragma unroll
            for (int e = 0; e < 8; ++e) {
                int k = ks * 32 + kg * 8 + e;
                float v = (gr >= 0 && k < 50) ? w_hh[gr * 50 + k] : 0.0f;
                unsigned short hb = f2bf(v);
                Bhh[q][ks][e] = (short)hb;
                Bhl[q][ks][e] = (short)f2bf(v - bf2f(hb));
            }
    }

    // ---- stage x(0) into buf 0 ----
    if (INSEL == 0) {
        if (tid < MBK * 8) {
            int b = tid >> 3, k = tid & 7;
            float v = xf[((size_t)(b0 + b) * T_STEPS + 0) * 8 + k];
            unsigned short hb = f2bf(v);
            x_hi[0][b * KP + k] = (short)hb;
            x_lo[0][b * KP + k] = (short)f2bf(v - bf2f(hb));
        }
    } else {
        int b = tid >> 4, j = tid & 15;
        if (j < 13) {
            uint4v v = *(const uint4v*)&xp[((size_t)(b0 + b) * T_STEPS + 0) * XCOLS + j * 4];
            short4v hs, ls;
            #pragma unroll
            for (int e = 0; e < 4; ++e) {
                short hb = (short)(v[e] >> 16), lb = (short)(v[e] & 0xffffu);
                if (j == 12 && e >= 2) { hb = 0; lb = 0; }
                hs[e] = hb; ls[e] = lb;
            }
            *(short4v*)&x_hi[0][b * KP + j * 4] = hs;
            *(short4v*)&x_lo[0][b * KP + j * 4] = ls;
        }
    }

    float cst[4] = {0.0f, 0.0f, 0.0f, 0.0f};
    __syncthreads();

    // ---- scan ----
    for (int t = 0; t < T_STEPS; ++t) {
        const int cur = t & 1;

        // phase 1: A-frags from LDS, MFMA, C -> LDS
        short8 Axh[KX], Axl[KX], Ahh[2], Ahl[2];
        #pragma unroll
        for (int ks = 0; ks < KX; ++ks) {
            Axh[ks] = *(const short8*)&x_hi[cur][col * KP + ks * 32 + kg * 8];
            Axl[ks] = *(const short8*)&x_lo[cur][col * KP + ks * 32 + kg * 8];
        }
        #pragma unroll
        for (int ks = 0; ks < 2; ++ks) {
            Ahh[ks] = *(const short8*)&h_hi[col * KP + ks * 32 + kg * 8];
            Ahl[ks] = *(const short8*)&h_lo[col * KP + ks * 32 + kg * 8];
        }

        f32x4 acc[4];
        #pragma unroll
        for (int q = 0; q < 4; ++q) acc[q] = (f32x4){bv[q], bv[q], bv[q], bv[q]};

        #pragma unroll
        for (int ks = 0; ks < KX; ++ks) {
            #pragma unroll
            for (int q = 0; q < 4; ++q)
                acc[q] = __builtin_amdgcn_mfma_f32_16x16x32_bf16(Axh[ks], Bxh[q][ks], acc[q], 0, 0, 0);
            #pragma unroll
            for (int q = 0; q < 4; ++q)
                acc[q] = __builtin_amdgcn_mfma_f32_16x16x32_bf16(Axl[ks], Bxh[q][ks], acc[q], 0, 0, 0);
            #pragma unroll
            for (int q = 0; q < 4; ++q)
                acc[q] = __builtin_amdgcn_mfma_f32_16x16x32_bf16(Axh[ks], Bxl[q][ks], acc[q], 0, 0, 0);
        }
        #pragma unroll
        for (int ks = 0; ks < 2; ++ks) {
            #pragma unroll
            for (int q = 0; q < 4; ++q)
                acc[q] = __builtin_amdgcn_mfma_f32_16x16x32_bf16(Ahh[ks], Bhh[q][ks], acc[q], 0, 0, 0);
            #pragma unroll
            for (int q = 0; q < 4; ++q)
                acc[q] = __builtin_amdgcn_mfma_f32_16x16x32_bf16(Ahl[ks], Bhh[q][ks], acc[q], 0, 0, 0);
            #pragma unroll
            for (int q = 0; q < 4; ++q)
                acc[q] = __builtin_amdgcn_mfma_f32_16x16x32_bf16(Ahh[ks], Bhl[q][ks], acc[q], 0, 0, 0);
        }

        // C layout: row(batch) = kg*4 + r, col(N') = tile*16 + col
        #pragma unroll
        for (int q = 0; q < 4; ++q)
            if (q < ntw) {
                int tile = base + q;
                #pragma unroll
                for (int r = 0; r < 4; ++r)
                    Cl[(kg * 4 + r) * SP + tile * 16 + col] = acc[q][r];
            }
        __syncthreads();

        // phase 2: issue x(t+1) loads -> cell update -> commit x(t+1)
        const bool ld = (t + 1 < T_STEPS);
        uint4v xv; float xfv = 0.0f;
        if (ld) {
            if (INSEL == 0) {
                if (tid < MBK * 8)
                    xfv = xf[((size_t)(b0 + (tid >> 3)) * T_STEPS + (t + 1)) * 8 + (tid & 7)];
            } else {
                if ((tid & 15) < 13)
                    xv = *(const uint4v*)&xp[((size_t)(b0 + (tid >> 4)) * T_STEPS + (t + 1)) * XCOLS + (tid & 15) * 4];
            }
        }

        #pragma unroll
        for (int r = 0; r < 4; ++r) {
            int i = tid + r * NTHR;
            if (i < 50 * MBK) {
                int n = i >> 4, b = i & 15;
                f32x4 gv = *(const f32x4*)&Cl[b * SP + 4 * n];
                float ig = fast_sigmoid(gv[0]);
                float fg = fast_sigmoid(gv[1]);
                float gg = fast_tanh(gv[2]);
                float og = fast_sigmoid(gv[3]);
                float c = fmaf(fg, cst[r], ig * gg);
                cst[r] = c;
                float h = og * fast_tanh(c);
                unsigned short hb = f2bf(h);
                unsigned short lb = f2bf(h - bf2f(hb));
                h_hi[b * KP + n] = (short)hb;
                h_lo[b * KP + n] = (short)lb;
                if (!LAST)
                    xout[((size_t)(b0 + b) * T_STEPS + t) * XCOLS + n] = ((unsigned)hb << 16) | lb;
                if (LAST && t == T_STEPS - 1)
                    hf[b * 56 + n] = h;
            }
        }

        if (ld) {
            int buf = (t + 1) & 1;
            if (INSEL == 0) {
                if (tid < MBK * 8) {
                    int b = tid >> 3, k = tid & 7;
                    unsigned short hb = f2bf(xfv);
                    x_hi[buf][b * KP + k] = (short)hb;
                    x_lo[buf][b * KP + k] = (short)f2bf(xfv - bf2f(hb));
                }
            } else {
                int b = tid >> 4, j = tid & 15;
                if (j < 13) {
                    short4v hs, ls;
                    #pragma unroll
                    for (int e = 0; e < 4; ++e) {
                        short hb = (short)(xv[e] >> 16), lb = (short)(xv[e] & 0xffffu);
                        if (j == 12 && e >= 2) { hb = 0; lb = 0; }
                        hs[e] = hb; ls[e] = lb;
                    }
                    *(short4v*)&x_hi[buf][b * KP + j * 4] = hs;
                    *(short4v*)&x_lo[buf][b * KP + j * 4] = ls;
                }
            }
        }
        __syncthreads();
    }

    // ---- FC epilogue (last layer) ----
    if (LAST) {
        if (tid < MBK * 6) {
            int b = tid / 6, o = tid - b * 6;
            float a = b_fc[o];
            #pragma unroll
            for (int n = 0; n < 50; ++n)
                a = fmaf(w_fc[o * 50 + n], hf[b * 56 + n], a);
            out[(size_t)(b0 + b) * 6 + o] = a;
        }
    }
}

extern "C" void kernel_launch(void* const* d_in, const int* in_sizes, int n_in,
                              void* d_out, int out_size, void* d_ws, size_t ws_size,
                              hipStream_t stream) {
    (void)in_sizes; (void)n_in; (void)d_ws; (void)ws_size; (void)out_size;

    const float* x     = (const float*)d_in[0];
    const float* w_ih0 = (const float*)d_in[1];
    const float* w_hh0 = (const float*)d_in[2];
    const float* b_ih0 = (const float*)d_in[3];
    const float* b_hh0 = (const float*)d_in[4];
    const float* w_ih1 = (const float*)d_in[5];
    const float* w_hh1 = (const float*)d_in[6];
    const float* b_ih1 = (const float*)d_in[7];
    const float* b_hh1 = (const float*)d_in[8];
    const float* w_ih2 = (const float*)d_in[9];
    const float* w_hh2 = (const float*)d_in[10];
    const float* b_ih2 = (const float*)d_in[11];
    const float* b_hh2 = (const float*)d_in[12];
    const float* w_fc  = (const float*)d_in[13];
    const float* b_fc  = (const float*)d_in[14];
    float* out = (float*)d_out;

    dim3 grid(BTOT / MBK), block(NTHR);
    lstm_mfma<8,  0, 1><<<grid, block, 0, stream>>>(x,       w_ih0, w_hh0, b_ih0, b_hh0, nullptr, nullptr, out);
    lstm_mfma<50, 1, 2><<<grid, block, 0, stream>>>(nullptr, w_ih1, w_hh1, b_ih1, b_hh1, nullptr, nullptr, out);
    lstm_mfma<50, 2, 0><<<grid, block, 0, stream>>>(nullptr, w_ih2, w_hh2, b_ih2, b_hh2, w_fc,    b_fc,    out);
}

// Round 4
// 889.145 us; speedup vs baseline: 99.2686x; 1.1589x over previous
//
#include <hip/hip_runtime.h>
#include <hip/hip_bf16.h>
#include <cstddef>

#define T_STEPS 256
#define BTOT 4096
#define MBK 8        // batches per block (grid 512 -> 2 blocks/CU)
#define NTHR 256     // 4 waves
#define KP 72        // K stride (shorts) for 16-row LDS activation tiles
#define SP 212       // C exchange row stride (floats)
#define XCOLS 52     // packed inter-layer timeseries cols (50 + pad)

typedef __attribute__((ext_vector_type(8))) short  short8;   // bf16 MFMA frag
typedef __attribute__((ext_vector_type(4))) short  short4v;
typedef __attribute__((ext_vector_type(4))) float  f32x4;
typedef __attribute__((ext_vector_type(4))) unsigned uint4v;

// Inter-layer timeseries, (hi<<16)|lo packed bf16 pair per value ~= fp32.
__device__ unsigned g_x01[(size_t)BTOT * T_STEPS * XCOLS];
__device__ unsigned g_x12[(size_t)BTOT * T_STEPS * XCOLS];

__device__ __forceinline__ float fast_sigmoid(float x) {
    float e = __builtin_amdgcn_exp2f(-1.4426950408889634f * x);
    return __builtin_amdgcn_rcpf(1.0f + e);
}
__device__ __forceinline__ float fast_tanh(float x) {
    float e = __builtin_amdgcn_exp2f(2.8853900817779268f * x);
    return 1.0f - 2.0f * __builtin_amdgcn_rcpf(1.0f + e);
}
__device__ __forceinline__ unsigned short f2bf(float x) {
    union { __hip_bfloat16 b; unsigned short s; } u;
    u.b = __float2bfloat16(x);
    return u.s;
}
__device__ __forceinline__ float bf2f(unsigned short s) {
    union { unsigned u; float f; } v; v.u = (unsigned)s << 16; return v.f;
}

// bf16-split MFMA LSTM layer, 8 batches/block, 2 blocks/CU.
// Gate order N' = 4*n + g (g: 0=i,1=f,2=g,3=o). Wave w owns n-tiles
// {0..3},{4..6},{7..9},{10..12}. Cell update is WAVE-LOCAL (no mid-step
// barrier): wave writes its C cols to Cl, reads back its own (n,b) items.
// h double-buffered -> ONE raw s_barrier per step (no vmcnt drain).
template<int D, int INSEL, int OUTSEL>
__global__ __launch_bounds__(NTHR, 2) void lstm_mfma(
    const float* __restrict__ xf,
    const float* __restrict__ w_ih, const float* __restrict__ w_hh,
    const float* __restrict__ b_ih, const float* __restrict__ b_hh,
    const float* __restrict__ w_fc, const float* __restrict__ b_fc,
    float* __restrict__ out)
{
    constexpr int  KX   = (D + 31) / 32;
    constexpr bool LAST = (OUTSEL == 0);

    const unsigned* xp  = (INSEL == 1) ? g_x01 : g_x12;
    unsigned*      xout = (OUTSEL == 1) ? g_x01 : g_x12;

    __shared__ __align__(16) short h_hi[2][16 * KP], h_lo[2][16 * KP];
    __shared__ __align__(16) short x_hi[2][16 * KP], x_lo[2][16 * KP];
    __shared__ __align__(16) float Cl[8 * SP];
    __shared__ __align__(16) float hf[MBK * 56];

    const int tid  = threadIdx.x;
    const int w    = tid >> 6;
    const int lane = tid & 63;
    const int col  = lane & 15;      // A-row (batch) / C col-within-tile
    const int kg   = lane >> 4;      // k-group 0..3
    const int b0   = blockIdx.x * MBK;
    const int base = w ? 3 * w + 1 : 0;
    const int ntw  = w ? 3 : 4;

    // ---- prologue: zero LDS act tiles (rows 8..15 stay zero forever) ----
    for (int i = tid; i < 16 * KP; i += NTHR) {
        h_hi[0][i] = 0; h_hi[1][i] = 0; h_lo[0][i] = 0; h_lo[1][i] = 0;
        x_hi[0][i] = 0; x_hi[1][i] = 0; x_lo[0][i] = 0; x_lo[1][i] = 0;
    }

    // ---- weights -> B-frags (hi/lo), bias per (q,col) ----
    short8 Bxh[4][KX], Bxl[4][KX], Bhh[4][2], Bhl[4][2];
    float  bv[4];
    #pragma unroll
    for (int q = 0; q < 4; ++q) {
        int tile = base + q;
        int gp = tile * 16 + col;                        // N'
        int gr = (gp < 200) ? ((gp & 3) * 50 + (gp >> 2)) : -1;
        bv[q] = (gr >= 0) ? (b_ih[gr] + b_hh[gr]) : 0.0f;
        #pragma unroll
        for (int ks = 0; ks < KX; ++ks)
            #pragma unroll
            for (int e = 0; e < 8; ++e) {
                int k = ks * 32 + kg * 8 + e;
                float v = (gr >= 0 && k < D) ? w_ih[gr * D + k] : 0.0f;
                unsigned short hb = f2bf(v);
                Bxh[q][ks][e] = (short)hb;
                Bxl[q][ks][e] = (short)f2bf(v - bf2f(hb));
            }
        #pragma unroll
        for (int ks = 0; ks < 2; ++ks)
            #pragma unroll
            for (int e = 0; e < 8; ++e) {
                int k = ks * 32 + kg * 8 + e;
                float v = (gr >= 0 && k < 50) ? w_hh[gr * 50 + k] : 0.0f;
                unsigned short hb = f2bf(v);
                Bhh[q][ks][e] = (short)hb;
                Bhl[q][ks][e] = (short)f2bf(v - bf2f(hb));
            }
    }

    // ---- stage x(0) into buf 0 (batches 0..7 only) ----
    if (INSEL == 0) {
        if (tid < MBK * 8) {
            int b = tid >> 3, k = tid & 7;
            float v = xf[((size_t)(b0 + b) * T_STEPS + 0) * 8 + k];
            unsigned short hb = f2bf(v);
            x_hi[0][b * KP + k] = (short)hb;
            x_lo[0][b * KP + k] = (short)f2bf(v - bf2f(hb));
        }
    } else {
        int b = tid >> 4, j = tid & 15;
        if (b < MBK && j < 13) {
            uint4v v = *(const uint4v*)&xp[((size_t)(b0 + b) * T_STEPS + 0) * XCOLS + j * 4];
            short4v hs, ls;
            #pragma unroll
            for (int e = 0; e < 4; ++e) {
                short hb = (short)(v[e] >> 16), lb = (short)(v[e] & 0xffffu);
                if (j == 12 && e >= 2) { hb = 0; lb = 0; }
                hs[e] = hb; ls[e] = lb;
            }
            *(short4v*)&x_hi[0][b * KP + j * 4] = hs;
            *(short4v*)&x_lo[0][b * KP + j * 4] = ls;
        }
    }

    float cst[2] = {0.0f, 0.0f};
    __syncthreads();

    // ---- scan: one barrier per step ----
    for (int t = 0; t < T_STEPS; ++t) {
        const int cur = t & 1, nxt = cur ^ 1;

        // A-frags from LDS
        short8 Axh[KX], Axl[KX], Ahh[2], Ahl[2];
        #pragma unroll
        for (int ks = 0; ks < KX; ++ks) {
            Axh[ks] = *(const short8*)&x_hi[cur][col * KP + ks * 32 + kg * 8];
            Axl[ks] = *(const short8*)&x_lo[cur][col * KP + ks * 32 + kg * 8];
        }
        #pragma unroll
        for (int ks = 0; ks < 2; ++ks) {
            Ahh[ks] = *(const short8*)&h_hi[cur][col * KP + ks * 32 + kg * 8];
            Ahl[ks] = *(const short8*)&h_lo[cur][col * KP + ks * 32 + kg * 8];
        }

        // issue x(t+1) global loads early (hidden under MFMA + update)
        const bool ld = (t + 1 < T_STEPS);
        uint4v xv; float xfv = 0.0f;
        if (ld) {
            if (INSEL == 0) {
                if (tid < MBK * 8)
                    xfv = xf[((size_t)(b0 + (tid >> 3)) * T_STEPS + (t + 1)) * 8 + (tid & 7)];
            } else {
                if ((tid >> 4) < MBK && (tid & 15) < 13)
                    xv = *(const uint4v*)&xp[((size_t)(b0 + (tid >> 4)) * T_STEPS + (t + 1)) * XCOLS + (tid & 15) * 4];
            }
        }

        // MFMA: acc[q] = bias + x-part + h-part (3-term bf16 split)
        f32x4 acc[4];
        #pragma unroll
        for (int q = 0; q < 4; ++q) acc[q] = (f32x4){bv[q], bv[q], bv[q], bv[q]};
        #pragma unroll
        for (int ks = 0; ks < KX; ++ks) {
            #pragma unroll
            for (int q = 0; q < 4; ++q)
                acc[q] = __builtin_amdgcn_mfma_f32_16x16x32_bf16(Axh[ks], Bxh[q][ks], acc[q], 0, 0, 0);
            #pragma unroll
            for (int q = 0; q < 4; ++q)
                acc[q] = __builtin_amdgcn_mfma_f32_16x16x32_bf16(Axl[ks], Bxh[q][ks], acc[q], 0, 0, 0);
            #pragma unroll
            for (int q = 0; q < 4; ++q)
                acc[q] = __builtin_amdgcn_mfma_f32_16x16x32_bf16(Axh[ks], Bxl[q][ks], acc[q], 0, 0, 0);
        }
        #pragma unroll
        for (int ks = 0; ks < 2; ++ks) {
            #pragma unroll
            for (int q = 0; q < 4; ++q)
                acc[q] = __builtin_amdgcn_mfma_f32_16x16x32_bf16(Ahh[ks], Bhh[q][ks], acc[q], 0, 0, 0);
            #pragma unroll
            for (int q = 0; q < 4; ++q)
                acc[q] = __builtin_amdgcn_mfma_f32_16x16x32_bf16(Ahl[ks], Bhh[q][ks], acc[q], 0, 0, 0);
            #pragma unroll
            for (int q = 0; q < 4; ++q)
                acc[q] = __builtin_amdgcn_mfma_f32_16x16x32_bf16(Ahh[ks], Bhl[q][ks], acc[q], 0, 0, 0);
        }

        // C-write, wave-local, valid batch rows only (kg<2 -> rows 0..7).
        // banks = col + kg*16 + (212*r)%32 -> conflict-free.
        if (kg < 2) {
            #pragma unroll
            for (int q = 0; q < 4; ++q)
                if (q < ntw) {
                    int tile = base + q;
                    #pragma unroll
                    for (int r = 0; r < 4; ++r)
                        Cl[(kg * 4 + r) * SP + tile * 16 + col] = acc[q][r];
                }
        }
        // same-wave RAW: compiler inserts lgkmcnt wait; no barrier needed.

        // cell update: wave-owned items (n,b), n in wave's tile range
        #pragma unroll
        for (int it = 0; it < 2; ++it) {
            int item = it * 64 + lane;
            int nl = item >> 3, b = item & 7;
            if (nl < ntw * 4) {
                int n = base * 4 + nl;
                f32x4 gv = *(const f32x4*)&Cl[b * SP + 4 * n];
                float ig = fast_sigmoid(gv[0]);
                float fg = fast_sigmoid(gv[1]);
                float gg = fast_tanh(gv[2]);
                float og = fast_sigmoid(gv[3]);
                float c = fmaf(fg, cst[it], ig * gg);
                cst[it] = c;
                float h = og * fast_tanh(c);
                unsigned short hb = f2bf(h);
                unsigned short lb = f2bf(h - bf2f(hb));
                h_hi[nxt][b * KP + n] = (short)hb;
                h_lo[nxt][b * KP + n] = (short)lb;
                if (!LAST)
                    xout[((size_t)(b0 + b) * T_STEPS + t) * XCOLS + n] = ((unsigned)hb << 16) | lb;
                if (LAST && t == T_STEPS - 1)
                    hf[b * 56 + n] = h;
            }
        }

        // commit x(t+1)
        if (ld) {
            if (INSEL == 0) {
                if (tid < MBK * 8) {
                    int b = tid >> 3, k = tid & 7;
                    unsigned short hb = f2bf(xfv);
                    x_hi[nxt][b * KP + k] = (short)hb;
                    x_lo[nxt][b * KP + k] = (short)f2bf(xfv - bf2f(hb));
                }
            } else {
                int b = tid >> 4, j = tid & 15;
                if (b < MBK && j < 13) {
                    short4v hs, ls;
                    #pragma unroll
                    for (int e = 0; e < 4; ++e) {
                        short hb = (short)(xv[e] >> 16), lb = (short)(xv[e] & 0xffffu);
                        if (j == 12 && e >= 2) { hb = 0; lb = 0; }
                        hs[e] = hb; ls[e] = lb;
                    }
                    *(short4v*)&x_hi[nxt][b * KP + j * 4] = hs;
                    *(short4v*)&x_lo[nxt][b * KP + j * 4] = ls;
                }
            }
        }

        // single end-of-step barrier: drain LDS only (NOT the global stores)
        asm volatile("s_waitcnt lgkmcnt(0)" ::: "memory");
        __builtin_amdgcn_sched_barrier(0);
        __builtin_amdgcn_s_barrier();
        __builtin_amdgcn_sched_barrier(0);
    }

    // ---- FC epilogue (last layer) ----
    if (LAST) {
        if (tid < MBK * 6) {
            int b = tid / 6, o = tid - b * 6;
            float a = b_fc[o];
            #pragma unroll
            for (int n = 0; n < 50; ++n)
                a = fmaf(w_fc[o * 50 + n], hf[b * 56 + n], a);
            out[(size_t)(b0 + b) * 6 + o] = a;
        }
    }
}

extern "C" void kernel_launch(void* const* d_in, const int* in_sizes, int n_in,
                              void* d_out, int out_size, void* d_ws, size_t ws_size,
                              hipStream_t stream) {
    (void)in_sizes; (void)n_in; (void)d_ws; (void)ws_size; (void)out_size;

    const float* x     = (const float*)d_in[0];
    const float* w_ih0 = (const float*)d_in[1];
    const float* w_hh0 = (const float*)d_in[2];
    const float* b_ih0 = (const float*)d_in[3];
    const float* b_hh0 = (const float*)d_in[4];
    const float* w_ih1 = (const float*)d_in[5];
    const float* w_hh1 = (const float*)d_in[6];
    const float* b_ih1 = (const float*)d_in[7];
    const float* b_hh1 = (const float*)d_in[8];
    const float* w_ih2 = (const float*)d_in[9];
    const float* w_hh2 = (const float*)d_in[10];
    const float* b_ih2 = (const float*)d_in[11];
    const float* b_hh2 = (const float*)d_in[12];
    const float* w_fc  = (const float*)d_in[13];
    const float* b_fc  = (const float*)d_in[14];
    float* out = (float*)d_out;

    dim3 grid(BTOT / MBK), block(NTHR);
    lstm_mfma<8,  0, 1><<<grid, block, 0, stream>>>(x,       w_ih0, w_hh0, b_ih0, b_hh0, nullptr, nullptr, out);
    lstm_mfma<50, 1, 2><<<grid, block, 0, stream>>>(nullptr, w_ih1, w_hh1, b_ih1, b_hh1, nullptr, nullptr, out);
    lstm_mfma<50, 2, 0><<<grid, block, 0, stream>>>(nullptr, w_ih2, w_hh2, b_ih2, b_hh2, w_fc,    b_fc,    out);
}

// Round 5
// 432.522 us; speedup vs baseline: 204.0686x; 2.0557x over previous
//
#include <hip/hip_runtime.h>
#include <hip/hip_bf16.h>
#include <cstddef>

// Fused 3-layer LSTM, wavefront-pipelined across layers inside one block.
// Block = 16 batches, 768 threads = 12 waves, role-specialized:
//   w0-2:  L0 (tiles 5+4+4 of 13)
//   w3-6:  L1 (3 tiles each, tiles 0..11)
//   w7-10: L2 (3 tiles each, tiles 0..11)
//   w11:   orphan (tile 12 of L1 AND L2)
// Skewed schedule: iter it -> L0@t=it, L1@t=it-1, L2@t=it-2.
// Inter-layer h passes via LDS act tiles as bf16 (hi,lo) pairs; NO global
// timeseries (round-4's 875MB HBM round-trip eliminated).

#define T_STEPS 256
#define BTOT    4096
#define NTHR    768
#define KP0     72      // L0 act row stride (shorts): [x 0..7 | h 8..57 | pad], 2 K-steps
#define KP1     136     // L1/L2 act row stride: [x 0..49 | h 50..99 | pad], 4 K-steps
#define SPC     212     // Cl row stride (floats), mod 32 = 20 -> conflict-light

typedef __attribute__((ext_vector_type(8))) short    short8;
typedef __attribute__((ext_vector_type(4))) float    f32x4;

// LDS layout (bytes)
#define OFF_A0H 0                  // 3 bufs * 16*72 shorts = 6912 B
#define OFF_A0L 6912
#define OFF_A1H 13824              // 2 bufs * 16*136 shorts = 8704 B
#define OFF_A1L 22528
#define OFF_A2H 31232
#define OFF_A2L 39936
#define OFF_CL0 48640              // 16*212*4 = 13568 B each
#define OFF_CL1 62208
#define OFF_CL2 75776
#define OFF_HF  89344              // 16*56*4 = 3584 B
#define LDS_TOTAL 92928

#define BAR() do { \
    asm volatile("s_waitcnt lgkmcnt(0)" ::: "memory"); \
    __builtin_amdgcn_sched_barrier(0); \
    __builtin_amdgcn_s_barrier(); \
    __builtin_amdgcn_sched_barrier(0); \
} while (0)

__device__ __forceinline__ float fast_sigmoid(float x) {
    float e = __builtin_amdgcn_exp2f(-1.4426950408889634f * x);
    return __builtin_amdgcn_rcpf(1.0f + e);
}
__device__ __forceinline__ float fast_tanh(float x) {
    float e = __builtin_amdgcn_exp2f(2.8853900817779268f * x);
    return 1.0f - 2.0f * __builtin_amdgcn_rcpf(1.0f + e);
}
__device__ __forceinline__ unsigned short f2bf(float x) {
    union { __hip_bfloat16 b; unsigned short s; } u;
    u.b = __float2bfloat16(x);
    return u.s;
}
__device__ __forceinline__ float bf2f(unsigned short s) {
    union { unsigned u; float f; } v; v.u = (unsigned)s << 16; return v.f;
}

// Load NT weight tiles into (hi,lo) bf16 B-frags + bias. K-packed [w_ih | w_hh].
template<int NT, int KS, int XK>
__device__ __forceinline__ void load_wb(int T0, int lane,
    const float* __restrict__ w_ih, const float* __restrict__ w_hh,
    const float* __restrict__ b_ih, const float* __restrict__ b_hh,
    short8 (&Bh)[NT][KS], short8 (&Bl)[NT][KS], float (&bv)[NT])
{
    const int col = lane & 15, kg = lane >> 4;
    #pragma unroll
    for (int q = 0; q < NT; ++q) {
        int gp = (T0 + q) * 16 + col;                    // N' = 4n+g
        int gr = (gp < 200) ? ((gp & 3) * 50 + (gp >> 2)) : -1;
        bv[q] = (gr >= 0) ? (b_ih[gr] + b_hh[gr]) : 0.0f;
        #pragma unroll
        for (int ks = 0; ks < KS; ++ks)
            #pragma unroll
            for (int e = 0; e < 8; ++e) {
                int k = ks * 32 + kg * 8 + e;
                float v = 0.0f;
                if (gr >= 0) {
                    if (k < XK) v = w_ih[gr * XK + k];
                    else if (k < XK + 50) v = w_hh[gr * 50 + (k - XK)];
                }
                unsigned short hb = f2bf(v);
                Bh[q][ks][e] = (short)hb;
                Bl[q][ks][e] = (short)f2bf(v - bf2f(hb));
            }
    }
}

// One layer-step for one wave's NT tiles (MFMA + wave-local cell update).
template<int NT, int KS, int KPW, int HOFF, bool WRB, bool LASTL>
__device__ __forceinline__ void step_body(
    int t, int T0, int lane,
    const short* Arh, const short* Arl,          // read act buf (row base)
    float* ClL,
    short* Awh, short* Awl,                      // own-h write buf
    short* Axh, short* Axl, int KPN,             // boundary x write buf (if WRB)
    float* hfp,
    const short8 (&Bh)[NT][KS], const short8 (&Bl)[NT][KS],
    const float (&bv)[NT], float (&cst)[NT])
{
    const int col = lane & 15, kg = lane >> 4;

    short8 Ah[KS], Al[KS];
    #pragma unroll
    for (int ks = 0; ks < KS; ++ks) {
        Ah[ks] = *(const short8*)&Arh[col * KPW + ks * 32 + kg * 8];
        Al[ks] = *(const short8*)&Arl[col * KPW + ks * 32 + kg * 8];
    }

    f32x4 acc[NT];
    #pragma unroll
    for (int q = 0; q < NT; ++q) acc[q] = (f32x4){bv[q], bv[q], bv[q], bv[q]};
    #pragma unroll
    for (int ks = 0; ks < KS; ++ks)
        #pragma unroll
        for (int q = 0; q < NT; ++q)
            acc[q] = __builtin_amdgcn_mfma_f32_16x16x32_bf16(Ah[ks], Bh[q][ks], acc[q], 0, 0, 0);
    #pragma unroll
    for (int ks = 0; ks < KS; ++ks)
        #pragma unroll
        for (int q = 0; q < NT; ++q)
            acc[q] = __builtin_amdgcn_mfma_f32_16x16x32_bf16(Al[ks], Bh[q][ks], acc[q], 0, 0, 0);
    #pragma unroll
    for (int ks = 0; ks < KS; ++ks)
        #pragma unroll
        for (int q = 0; q < NT; ++q)
            acc[q] = __builtin_amdgcn_mfma_f32_16x16x32_bf16(Ah[ks], Bl[q][ks], acc[q], 0, 0, 0);

    // C -> Cl (wave-local): row = batch = kg*4+r, col = (T0+q)*16 + col
    #pragma unroll
    for (int q = 0; q < NT; ++q)
        #pragma unroll
        for (int r = 0; r < 4; ++r)
            ClL[(kg * 4 + r) * SPC + (T0 + q) * 16 + col] = acc[q][r];

    // cell update: lane -> (unit nl = lane>>4 within tile, batch b = lane&15)
    const int nl = lane >> 4, b = lane & 15;
    #pragma unroll
    for (int q = 0; q < NT; ++q) {
        int n = (T0 + q) * 4 + nl;
        if (n < 50) {
            f32x4 gv = *(const f32x4*)&ClL[b * SPC + 4 * n];
            float ig = fast_sigmoid(gv[0]);
            float fg = fast_sigmoid(gv[1]);
            float gg = fast_tanh(gv[2]);
            float og = fast_sigmoid(gv[3]);
            float c = fmaf(fg, cst[q], ig * gg);
            cst[q] = c;
            float h = og * fast_tanh(c);
            unsigned short hb = f2bf(h);
            unsigned short lb = f2bf(h - bf2f(hb));
            Awh[b * KPW + HOFF + n] = (short)hb;
            Awl[b * KPW + HOFF + n] = (short)lb;
            if (WRB) {
                Axh[b * KPN + n] = (short)hb;
                Axl[b * KPN + n] = (short)lb;
            }
            if (LASTL && t == T_STEPS - 1) hfp[b * 56 + n] = h;
        }
    }
}

// L0 role: NT tiles + (optionally) x prefetch duty (SOFF = item base, -1 = none)
template<int NT>
__device__ void role_l0(int T0, int SOFF, int lane, int b0,
    const float* __restrict__ xf,
    const float* w_ih, const float* w_hh, const float* b_ih, const float* b_hh,
    short* A0h, short* A0l, float* Cl0, short* A1h, short* A1l)
{
    short8 Bh[NT][2], Bl[NT][2]; float bv[NT], cst[NT];
    load_wb<NT, 2, 8>(T0, lane, w_ih, w_hh, b_ih, b_hh, Bh, Bl, bv);
    #pragma unroll
    for (int q = 0; q < NT; ++q) cst[q] = 0.0f;

    float s0 = 0.0f, s1 = 0.0f; int sb = 0, sj = 0;
    if (SOFF >= 0) {
        int item = SOFF + lane; sb = item >> 3; sj = item & 7;
        s0 = xf[((size_t)(b0 + sb) * T_STEPS + 2) * 8 + sj];
        s1 = xf[((size_t)(b0 + sb) * T_STEPS + 3) * 8 + sj];
    }

    for (int it = 0; it < T_STEPS + 2; ++it) {
        if (SOFF >= 0 && it <= 253) {                   // commit x(it+2), 2-iter flight
            float v = (it & 1) ? s1 : s0;
            unsigned short hb = f2bf(v), lb = f2bf(v - bf2f(hb));
            int bi = (it + 2) % 3;
            A0h[bi * (16 * KP0) + sb * KP0 + sj] = (short)hb;
            A0l[bi * (16 * KP0) + sb * KP0 + sj] = (short)lb;
            if (it <= 251) {
                float nv = xf[((size_t)(b0 + sb) * T_STEPS + (it + 4)) * 8 + sj];
                if (it & 1) s1 = nv; else s0 = nv;
            }
        }
        if (it < T_STEPS) {
            int t = it;
            step_body<NT, 2, KP0, 8, true, false>(t, T0, lane,
                A0h + (t % 3) * (16 * KP0), A0l + (t % 3) * (16 * KP0), Cl0,
                A0h + ((t + 1) % 3) * (16 * KP0), A0l + ((t + 1) % 3) * (16 * KP0),
                A1h + (t & 1) * (16 * KP1), A1l + (t & 1) * (16 * KP1), KP1,
                nullptr, Bh, Bl, bv, cst);
        }
        BAR();
    }
}

// L1 (SKEW=1, writes boundary to A2) or L2 (SKEW=2, LAST) role, 3 tiles.
template<bool LASTL>
__device__ void role_mid(int T0, int SKEW, int lane,
    const float* w_ih, const float* w_hh, const float* b_ih, const float* b_hh,
    short* Arh, short* Arl, float* ClL, short* Axh, short* Axl, float* hfp)
{
    short8 Bh[3][4], Bl[3][4]; float bv[3], cst[3] = {0.0f, 0.0f, 0.0f};
    load_wb<3, 4, 50>(T0, lane, w_ih, w_hh, b_ih, b_hh, Bh, Bl, bv);

    for (int it = 0; it < T_STEPS + 2; ++it) {
        int t = it - SKEW;
        if (t >= 0 && t < T_STEPS) {
            step_body<3, 4, KP1, 50, !LASTL, LASTL>(t, T0, lane,
                Arh + (t & 1) * (16 * KP1), Arl + (t & 1) * (16 * KP1), ClL,
                Arh + ((t + 1) & 1) * (16 * KP1), Arl + ((t + 1) & 1) * (16 * KP1),
                LASTL ? nullptr : Axh + (t & 1) * (16 * KP1),
                LASTL ? nullptr : Axl + (t & 1) * (16 * KP1), KP1,
                hfp, Bh, Bl, bv, cst);
        }
        BAR();
    }
}

// Orphan: tile 12 of L1 and tile 12 of L2 in one wave.
__device__ void role_orphan(int lane,
    const float* w_ih1, const float* w_hh1, const float* b_ih1, const float* b_hh1,
    const float* w_ih2, const float* w_hh2, const float* b_ih2, const float* b_hh2,
    short* A1h, short* A1l, short* A2h, short* A2l,
    float* Cl1, float* Cl2, float* hfp)
{
    short8 B1h[1][4], B1l[1][4], B2h[1][4], B2l[1][4];
    float bv1[1], bv2[1], cst1[1] = {0.0f}, cst2[1] = {0.0f};
    load_wb<1, 4, 50>(12, lane, w_ih1, w_hh1, b_ih1, b_hh1, B1h, B1l, bv1);
    load_wb<1, 4, 50>(12, lane, w_ih2, w_hh2, b_ih2, b_hh2, B2h, B2l, bv2);

    for (int it = 0; it < T_STEPS + 2; ++it) {
        int t1 = it - 1;
        if (t1 >= 0 && t1 < T_STEPS)
            step_body<1, 4, KP1, 50, true, false>(t1, 12, lane,
                A1h + (t1 & 1) * (16 * KP1), A1l + (t1 & 1) * (16 * KP1), Cl1,
                A1h + ((t1 + 1) & 1) * (16 * KP1), A1l + ((t1 + 1) & 1) * (16 * KP1),
                A2h + (t1 & 1) * (16 * KP1), A2l + (t1 & 1) * (16 * KP1), KP1,
                nullptr, B1h, B1l, bv1, cst1);
        int t2 = it - 2;
        if (t2 >= 0 && t2 < T_STEPS)
            step_body<1, 4, KP1, 50, false, true>(t2, 12, lane,
                A2h + (t2 & 1) * (16 * KP1), A2l + (t2 & 1) * (16 * KP1), Cl2,
                A2h + ((t2 + 1) & 1) * (16 * KP1), A2l + ((t2 + 1) & 1) * (16 * KP1),
                nullptr, nullptr, 0,
                hfp, B2h, B2l, bv2, cst2);
        BAR();
    }
}

__global__ __launch_bounds__(NTHR) void lstm_fused(
    const float* __restrict__ xf,
    const float* w_ih0, const float* w_hh0, const float* b_ih0, const float* b_hh0,
    const float* w_ih1, const float* w_hh1, const float* b_ih1, const float* b_hh1,
    const float* w_ih2, const float* w_hh2, const float* b_ih2, const float* b_hh2,
    const float* __restrict__ w_fc, const float* __restrict__ b_fc,
    float* __restrict__ out)
{
    extern __shared__ char sm[];
    short* A0h = (short*)(sm + OFF_A0H);
    short* A0l = (short*)(sm + OFF_A0L);
    short* A1h = (short*)(sm + OFF_A1H);
    short* A1l = (short*)(sm + OFF_A1L);
    short* A2h = (short*)(sm + OFF_A2H);
    short* A2l = (short*)(sm + OFF_A2L);
    float* Cl0 = (float*)(sm + OFF_CL0);
    float* Cl1 = (float*)(sm + OFF_CL1);
    float* Cl2 = (float*)(sm + OFF_CL2);
    float* hf  = (float*)(sm + OFF_HF);

    const int tid  = threadIdx.x;
    const int lane = tid & 63;
    const int wid  = tid >> 6;
    const int b0   = blockIdx.x * 16;

    for (int i = tid; i < LDS_TOTAL / 4; i += NTHR) ((int*)sm)[i] = 0;
    __syncthreads();

    // stage x(0) -> buf0, x(1) -> buf1
    if (tid < 128) {
        int b = tid >> 3, j = tid & 7;
        #pragma unroll
        for (int tt = 0; tt < 2; ++tt) {
            float v = xf[((size_t)(b0 + b) * T_STEPS + tt) * 8 + j];
            unsigned short hb = f2bf(v);
            A0h[tt * (16 * KP0) + b * KP0 + j] = (short)hb;
            A0l[tt * (16 * KP0) + b * KP0 + j] = (short)f2bf(v - bf2f(hb));
        }
    }
    __syncthreads();

    if (wid == 0)
        role_l0<5>(0, 0, lane, b0, xf, w_ih0, w_hh0, b_ih0, b_hh0, A0h, A0l, Cl0, A1h, A1l);
    else if (wid == 1)
        role_l0<4>(5, 64, lane, b0, xf, w_ih0, w_hh0, b_ih0, b_hh0, A0h, A0l, Cl0, A1h, A1l);
    else if (wid == 2)
        role_l0<4>(9, -1, lane, b0, xf, w_ih0, w_hh0, b_ih0, b_hh0, A0h, A0l, Cl0, A1h, A1l);
    else if (wid <= 6)
        role_mid<false>(3 * (wid - 3), 1, lane, w_ih1, w_hh1, b_ih1, b_hh1,
                        A1h, A1l, Cl1, A2h, A2l, nullptr);
    else if (wid <= 10)
        role_mid<true>(3 * (wid - 7), 2, lane, w_ih2, w_hh2, b_ih2, b_hh2,
                       A2h, A2l, Cl2, nullptr, nullptr, hf);
    else
        role_orphan(lane, w_ih1, w_hh1, b_ih1, b_hh1, w_ih2, w_hh2, b_ih2, b_hh2,
                    A1h, A1l, A2h, A2l, Cl1, Cl2, hf);

    __syncthreads();

    // FC epilogue: out[b][o] = b_fc[o] + sum_n w_fc[o][n] * h2_255[b][n]
    if (tid < 96) {
        int b = tid / 6, o = tid - b * 6;
        float a = b_fc[o];
        #pragma unroll
        for (int n = 0; n < 50; ++n)
            a = fmaf(w_fc[o * 50 + n], hf[b * 56 + n], a);
        out[(size_t)(b0 + b) * 6 + o] = a;
    }
}

extern "C" void kernel_launch(void* const* d_in, const int* in_sizes, int n_in,
                              void* d_out, int out_size, void* d_ws, size_t ws_size,
                              hipStream_t stream) {
    (void)in_sizes; (void)n_in; (void)d_ws; (void)ws_size; (void)out_size;

    const float* x     = (const float*)d_in[0];
    const float* w_ih0 = (const float*)d_in[1];
    const float* w_hh0 = (const float*)d_in[2];
    const float* b_ih0 = (const float*)d_in[3];
    const float* b_hh0 = (const float*)d_in[4];
    const float* w_ih1 = (const float*)d_in[5];
    const float* w_hh1 = (const float*)d_in[6];
    const float* b_ih1 = (const float*)d_in[7];
    const float* b_hh1 = (const float*)d_in[8];
    const float* w_ih2 = (const float*)d_in[9];
    const float* w_hh2 = (const float*)d_in[10];
    const float* b_ih2 = (const float*)d_in[11];
    const float* b_hh2 = (const float*)d_in[12];
    const float* w_fc  = (const float*)d_in[13];
    const float* b_fc  = (const float*)d_in[14];
    float* out = (float*)d_out;

    hipFuncSetAttribute((const void*)lstm_fused,
                        hipFuncAttributeMaxDynamicSharedMemorySize, LDS_TOTAL);
    lstm_fused<<<dim3(BTOT / 16), dim3(NTHR), LDS_TOTAL, stream>>>(
        x, w_ih0, w_hh0, b_ih0, b_hh0, w_ih1, w_hh1, b_ih1, b_hh1,
        w_ih2, w_hh2, b_ih2, b_hh2, w_fc, b_fc, out);
}

// Round 6
// 366.943 us; speedup vs baseline: 240.5391x; 1.1787x over previous
//
#include <hip/hip_runtime.h>
#include <hip/hip_bf16.h>
#include <cstddef>

// Fused 3-layer LSTM, wavefront-pipelined, swapped-operand MFMA.
// Block = 16 batches, 768 threads = 12 waves:
//   w0-2:  L0 tiles {0-4},{5-8},{9-12}; w2 also stages x from global
//   w3-6:  L1 tiles 3 each (0..11);  w7-10: L2 tiles 3 each (0..11)
//   w11:   orphan (tile 12 of L1 AND L2)
// Skew: iter it -> L0@t=it, L1@t=it-1, L2@t=it-2. One s_barrier per iter.
//
// Swapped MFMA: acc = mfma(W_frag, act_frag) -> C row = N' = 4n+g, col = batch.
// Lane (b=lane&15, kg=lane>>4) holds gates i,f,g,o (acc[q][0..3]) of unit
// n=(T0+q)*4+kg, batch b => cell update is fully in-register (no C exchange).
//
// Act LDS is fragment-major: addr_shorts(k,b) = (k>>3)*128 + b*8 + (k&7)
// -> wave frag reads are linear lane*16B (conflict-free).
// Bias rides a spare k-column (act==1.0): L0 k=58, L1/L2 k=100.

#define T_STEPS 256
#define BTOT    4096
#define NTHR    768

typedef __attribute__((ext_vector_type(8))) short short8;
typedef __attribute__((ext_vector_type(4))) float f32x4;

#define BAR() do { \
    asm volatile("s_waitcnt lgkmcnt(0)" ::: "memory"); \
    __builtin_amdgcn_sched_barrier(0); \
    __builtin_amdgcn_s_barrier(); \
    __builtin_amdgcn_sched_barrier(0); \
} while (0)

__device__ __forceinline__ float fast_sigmoid(float x) {
    float e = __builtin_amdgcn_exp2f(-1.4426950408889634f * x);
    return __builtin_amdgcn_rcpf(1.0f + e);
}
__device__ __forceinline__ float fast_tanh(float x) {
    float e = __builtin_amdgcn_exp2f(2.8853900817779268f * x);
    return 1.0f - 2.0f * __builtin_amdgcn_rcpf(1.0f + e);
}
__device__ __forceinline__ unsigned short f2bf(float x) {
    union { __hip_bfloat16 b; unsigned short s; } u;
    u.b = __float2bfloat16(x);
    return u.s;
}
__device__ __forceinline__ float bf2f(unsigned short s) {
    union { unsigned u; float f; } v; v.u = (unsigned)s << 16; return v.f;
}

// Weights -> (hi,lo) A-side frags. K-packed [w_ih(XK) | w_hh(50) | bias@BIASK].
// Frag: row N' = (T0+q)*16 + (lane&15), k = ks*32 + (lane>>4)*8 + e.
template<int NT, int KS, int XK, int BIASK>
__device__ __forceinline__ void load_wb(int T0, int lane,
    const float* __restrict__ w_ih, const float* __restrict__ w_hh,
    const float* __restrict__ b_ih, const float* __restrict__ b_hh,
    short8 (&Wh)[NT][KS], short8 (&Wl)[NT][KS])
{
    const int m = lane & 15, kg = lane >> 4;
    #pragma unroll
    for (int q = 0; q < NT; ++q) {
        int gp = (T0 + q) * 16 + m;                      // N' = 4n+g
        int gr = (gp < 200) ? ((gp & 3) * 50 + (gp >> 2)) : -1;
        #pragma unroll
        for (int ks = 0; ks < KS; ++ks)
            #pragma unroll
            for (int e = 0; e < 8; ++e) {
                int k = ks * 32 + kg * 8 + e;
                float v = 0.0f;
                if (gr >= 0) {
                    if (k < XK) v = w_ih[gr * XK + k];
                    else if (k < XK + 50) v = w_hh[gr * 50 + (k - XK)];
                    else if (k == BIASK) v = b_ih[gr] + b_hh[gr];
                }
                unsigned short hb = f2bf(v);
                Wh[q][ks][e] = (short)hb;
                Wl[q][ks][e] = (short)f2bf(v - bf2f(hb));
            }
    }
}

// One layer-step: frag reads -> 3-term MFMA -> in-register cell update -> h writes.
template<int NT, int KS, int HK, bool WRB, bool LASTL>
__device__ __forceinline__ void step_body(
    int t, int T0, int lane,
    const short* Arh, const short* Arl,      // act read buf
    short* Awh, short* Awl,                  // own act write buf (h at HK+n)
    short* Axh, short* Axl,                  // boundary buf (x-part, k=n), if WRB
    float* hfp,
    const short8 (&Wh)[NT][KS], const short8 (&Wl)[NT][KS],
    float (&cst)[NT])
{
    const int b = lane & 15, kg = lane >> 4;

    short8 Ah[KS], Al[KS];
    #pragma unroll
    for (int ks = 0; ks < KS; ++ks) {
        int ga = (ks * 4 + kg) * 128 + b * 8;
        Ah[ks] = *(const short8*)&Arh[ga];
        Al[ks] = *(const short8*)&Arl[ga];
    }

    f32x4 acc[NT];
    #pragma unroll
    for (int q = 0; q < NT; ++q) acc[q] = (f32x4){0.0f, 0.0f, 0.0f, 0.0f};
    #pragma unroll
    for (int ks = 0; ks < KS; ++ks)
        #pragma unroll
        for (int q = 0; q < NT; ++q)
            acc[q] = __builtin_amdgcn_mfma_f32_16x16x32_bf16(Wh[q][ks], Ah[ks], acc[q], 0, 0, 0);
    #pragma unroll
    for (int ks = 0; ks < KS; ++ks)
        #pragma unroll
        for (int q = 0; q < NT; ++q)
            acc[q] = __builtin_amdgcn_mfma_f32_16x16x32_bf16(Wl[q][ks], Ah[ks], acc[q], 0, 0, 0);
    #pragma unroll
    for (int ks = 0; ks < KS; ++ks)
        #pragma unroll
        for (int q = 0; q < NT; ++q)
            acc[q] = __builtin_amdgcn_mfma_f32_16x16x32_bf16(Wh[q][ks], Al[ks], acc[q], 0, 0, 0);

    #pragma unroll
    for (int q = 0; q < NT; ++q) {
        int n = (T0 + q) * 4 + kg;
        if (n < 50) {
            float ig = fast_sigmoid(acc[q][0]);
            float fg = fast_sigmoid(acc[q][1]);
            float gg = fast_tanh(acc[q][2]);
            float og = fast_sigmoid(acc[q][3]);
            float c  = fmaf(fg, cst[q], ig * gg);
            cst[q] = c;
            float h = og * fast_tanh(c);
            unsigned short hb = f2bf(h);
            unsigned short lb = f2bf(h - bf2f(hb));
            int k  = HK + n;
            int ad = (k >> 3) * 128 + b * 8 + (k & 7);
            Awh[ad] = (short)hb;
            Awl[ad] = (short)lb;
            if (WRB) {
                int ad2 = (n >> 3) * 128 + b * 8 + (n & 7);
                Axh[ad2] = (short)hb;
                Axl[ad2] = (short)lb;
            }
            if (LASTL && t == T_STEPS - 1) hfp[b * 56 + n] = h;
        }
    }
}

template<int NT, bool XSTAGE>
__device__ void role_l0(int T0, int lane, int b0, const float* __restrict__ xf,
    const float* w_ih, const float* w_hh, const float* b_ih, const float* b_hh,
    short (*A0h)[1024], short (*A0l)[1024],
    short (*A1h)[2048], short (*A1l)[2048])
{
    short8 Wh[NT][2], Wl[NT][2];
    load_wb<NT, 2, 8, 58>(T0, lane, w_ih, w_hh, b_ih, b_hh, Wh, Wl);
    float cst[NT];
    #pragma unroll
    for (int q = 0; q < NT; ++q) cst[q] = 0.0f;
    const int b = lane & 15, kg = lane >> 4;

    for (int it = 0; it < T_STEPS + 2; ++it) {
        const bool stg = XSTAGE && (kg == 0) && (it + 1 < T_STEPS);
        float4 x0, x1;
        if (stg) {
            const float* xr = &xf[((size_t)(b0 + b) * T_STEPS + (it + 1)) * 8];
            x0 = *(const float4*)xr;
            x1 = *(const float4*)(xr + 4);
        }
        if (it < T_STEPS) {
            int cur = it & 1, nxt = cur ^ 1;
            step_body<NT, 2, 8, true, false>(it, T0, lane,
                A0h[cur], A0l[cur], A0h[nxt], A0l[nxt],
                A1h[it & 1], A1l[it & 1], nullptr, Wh, Wl, cst);
        }
        if (stg) {
            int nb = (it + 1) & 1;
            short8 hi, lo;
            float vv0 = x0.x, vv1 = x0.y, vv2 = x0.z, vv3 = x0.w;
            float vv4 = x1.x, vv5 = x1.y, vv6 = x1.z, vv7 = x1.w;
            unsigned short hb;
            hb = f2bf(vv0); hi[0] = (short)hb; lo[0] = (short)f2bf(vv0 - bf2f(hb));
            hb = f2bf(vv1); hi[1] = (short)hb; lo[1] = (short)f2bf(vv1 - bf2f(hb));
            hb = f2bf(vv2); hi[2] = (short)hb; lo[2] = (short)f2bf(vv2 - bf2f(hb));
            hb = f2bf(vv3); hi[3] = (short)hb; lo[3] = (short)f2bf(vv3 - bf2f(hb));
            hb = f2bf(vv4); hi[4] = (short)hb; lo[4] = (short)f2bf(vv4 - bf2f(hb));
            hb = f2bf(vv5); hi[5] = (short)hb; lo[5] = (short)f2bf(vv5 - bf2f(hb));
            hb = f2bf(vv6); hi[6] = (short)hb; lo[6] = (short)f2bf(vv6 - bf2f(hb));
            hb = f2bf(vv7); hi[7] = (short)hb; lo[7] = (short)f2bf(vv7 - bf2f(hb));
            *(short8*)&A0h[nb][b * 8] = hi;      // k=0..7 -> granule b, linear
            *(short8*)&A0l[nb][b * 8] = lo;
        }
        BAR();
    }
}

template<bool LASTL>
__device__ void role_mid(int T0, int lane,
    const float* w_ih, const float* w_hh, const float* b_ih, const float* b_hh,
    short (*Arh)[2048], short (*Arl)[2048],
    short (*Axh)[2048], short (*Axl)[2048],
    float* hfp)
{
    constexpr int SKEW = LASTL ? 2 : 1;
    short8 Wh[3][4], Wl[3][4];
    load_wb<3, 4, 50, 100>(T0, lane, w_ih, w_hh, b_ih, b_hh, Wh, Wl);
    float cst[3] = {0.0f, 0.0f, 0.0f};

    for (int it = 0; it < T_STEPS + 2; ++it) {
        int t = it - SKEW;
        if (t >= 0 && t < T_STEPS) {
            int cur = t & 1, nxt = cur ^ 1;
            step_body<3, 4, 50, !LASTL, LASTL>(t, T0, lane,
                Arh[cur], Arl[cur], Arh[nxt], Arl[nxt],
                LASTL ? (short*)nullptr : Axh[t & 1],
                LASTL ? (short*)nullptr : Axl[t & 1],
                hfp, Wh, Wl, cst);
        }
        BAR();
    }
}

__device__ void role_orphan(int lane,
    const float* w_ih1, const float* w_hh1, const float* b_ih1, const float* b_hh1,
    const float* w_ih2, const float* w_hh2, const float* b_ih2, const float* b_hh2,
    short (*A1h)[2048], short (*A1l)[2048],
    short (*A2h)[2048], short (*A2l)[2048],
    float* hfp)
{
    short8 W1h[1][4], W1l[1][4], W2h[1][4], W2l[1][4];
    load_wb<1, 4, 50, 100>(12, lane, w_ih1, w_hh1, b_ih1, b_hh1, W1h, W1l);
    load_wb<1, 4, 50, 100>(12, lane, w_ih2, w_hh2, b_ih2, b_hh2, W2h, W2l);
    float c1[1] = {0.0f}, c2[1] = {0.0f};

    for (int it = 0; it < T_STEPS + 2; ++it) {
        int t1 = it - 1;
        if (t1 >= 0 && t1 < T_STEPS)
            step_body<1, 4, 50, true, false>(t1, 12, lane,
                A1h[t1 & 1], A1l[t1 & 1], A1h[(t1 + 1) & 1], A1l[(t1 + 1) & 1],
                A2h[t1 & 1], A2l[t1 & 1], nullptr, W1h, W1l, c1);
        int t2 = it - 2;
        if (t2 >= 0 && t2 < T_STEPS)
            step_body<1, 4, 50, false, true>(t2, 12, lane,
                A2h[t2 & 1], A2l[t2 & 1], A2h[(t2 + 1) & 1], A2l[(t2 + 1) & 1],
                nullptr, nullptr, hfp, W2h, W2l, c2);
        BAR();
    }
}

__global__ __launch_bounds__(NTHR) void lstm_fused(
    const float* __restrict__ xf,
    const float* w_ih0, const float* w_hh0, const float* b_ih0, const float* b_hh0,
    const float* w_ih1, const float* w_hh1, const float* b_ih1, const float* b_hh1,
    const float* w_ih2, const float* w_hh2, const float* b_ih2, const float* b_hh2,
    const float* __restrict__ w_fc, const float* __restrict__ b_fc,
    float* __restrict__ out)
{
    __shared__ __align__(16) short A0h[2][1024], A0l[2][1024];   // L0 act (K=64)
    __shared__ __align__(16) short A1h[2][2048], A1l[2][2048];   // L1 act (K=128)
    __shared__ __align__(16) short A2h[2][2048], A2l[2][2048];   // L2 act (K=128)
    __shared__ __align__(16) float hf[16 * 56];

    const int tid  = threadIdx.x;
    const int lane = tid & 63;
    const int wid  = tid >> 6;
    const int b0   = blockIdx.x * 16;

    for (int i = tid; i < 2048; i += NTHR) { ((short*)A0h)[i] = 0; ((short*)A0l)[i] = 0; }
    for (int i = tid; i < 4096; i += NTHR) {
        ((short*)A1h)[i] = 0; ((short*)A1l)[i] = 0;
        ((short*)A2h)[i] = 0; ((short*)A2l)[i] = 0;
    }
    __syncthreads();

    // bias act columns = 1.0 (both bufs); x(0) -> A0 buf0
    if (tid < 32) {
        int buf = tid >> 4, b = tid & 15;
        A0h[buf][(58 >> 3) * 128 + b * 8 + (58 & 7)] = (short)0x3F80;
        A1h[buf][(100 >> 3) * 128 + b * 8 + (100 & 7)] = (short)0x3F80;
        A2h[buf][(100 >> 3) * 128 + b * 8 + (100 & 7)] = (short)0x3F80;
    }
    if (tid < 16) {
        int b = tid;
        #pragma unroll
        for (int j = 0; j < 8; ++j) {
            float v = xf[((size_t)(b0 + b) * T_STEPS + 0) * 8 + j];
            unsigned short hb = f2bf(v);
            A0h[0][b * 8 + j] = (short)hb;
            A0l[0][b * 8 + j] = (short)f2bf(v - bf2f(hb));
        }
    }
    __syncthreads();

    if (wid == 0)
        role_l0<5, false>(0, lane, b0, xf, w_ih0, w_hh0, b_ih0, b_hh0, A0h, A0l, A1h, A1l);
    else if (wid == 1)
        role_l0<4, false>(5, lane, b0, xf, w_ih0, w_hh0, b_ih0, b_hh0, A0h, A0l, A1h, A1l);
    else if (wid == 2)
        role_l0<4, true>(9, lane, b0, xf, w_ih0, w_hh0, b_ih0, b_hh0, A0h, A0l, A1h, A1l);
    else if (wid <= 6)
        role_mid<false>(3 * (wid - 3), lane, w_ih1, w_hh1, b_ih1, b_hh1,
                        A1h, A1l, A2h, A2l, nullptr);
    else if (wid <= 10)
        role_mid<true>(3 * (wid - 7), lane, w_ih2, w_hh2, b_ih2, b_hh2,
                       A2h, A2l, nullptr, nullptr, hf);
    else
        role_orphan(lane, w_ih1, w_hh1, b_ih1, b_hh1, w_ih2, w_hh2, b_ih2, b_hh2,
                    A1h, A1l, A2h, A2l, hf);

    __syncthreads();

    if (tid < 96) {
        int b = tid / 6, o = tid - b * 6;
        float a = b_fc[o];
        #pragma unroll
        for (int n = 0; n < 50; ++n)
            a = fmaf(w_fc[o * 50 + n], hf[b * 56 + n], a);
        out[(size_t)(b0 + b) * 6 + o] = a;
    }
}

extern "C" void kernel_launch(void* const* d_in, const int* in_sizes, int n_in,
                              void* d_out, int out_size, void* d_ws, size_t ws_size,
                              hipStream_t stream) {
    (void)in_sizes; (void)n_in; (void)d_ws; (void)ws_size; (void)out_size;

    const float* x     = (const float*)d_in[0];
    const float* w_ih0 = (const float*)d_in[1];
    const float* w_hh0 = (const float*)d_in[2];
    const float* b_ih0 = (const float*)d_in[3];
    const float* b_hh0 = (const float*)d_in[4];
    const float* w_ih1 = (const float*)d_in[5];
    const float* w_hh1 = (const float*)d_in[6];
    const float* b_ih1 = (const float*)d_in[7];
    const float* b_hh1 = (const float*)d_in[8];
    const float* w_ih2 = (const float*)d_in[9];
    const float* w_hh2 = (const float*)d_in[10];
    const float* b_ih2 = (const float*)d_in[11];
    const float* b_hh2 = (const float*)d_in[12];
    const float* w_fc  = (const float*)d_in[13];
    const float* b_fc  = (const float*)d_in[14];
    float* out = (float*)d_out;

    lstm_fused<<<dim3(BTOT / 16), dim3(NTHR), 0, stream>>>(
        x, w_ih0, w_hh0, b_ih0, b_hh0, w_ih1, w_hh1, b_ih1, b_hh1,
        w_ih2, w_hh2, b_ih2, b_hh2, w_fc, b_fc, out);
}